// Round 1
// baseline (176.281 us; speedup 1.0000x reference)
//
#include <hip/hip_runtime.h>
#include <stdint.h>

#define B_ 4
#define N_ 4096
#define C_ 256
#define LOG2E 1.44269504088896340736f
#define SOFT_OFF 88.0f

typedef float f32x4 __attribute__((ext_vector_type(4)));
typedef float f32x16 __attribute__((ext_vector_type(16)));
typedef short s16x8 __attribute__((ext_vector_type(8)));
typedef __bf16 bf16x8 __attribute__((ext_vector_type(8)));
typedef _Float16 f16x8 __attribute__((ext_vector_type(8)));

static __device__ __forceinline__ unsigned short f2bf(float f) {
    union { float f; uint32_t u; } v; v.f = f;
    return (unsigned short)((v.u + 0x7FFFu + ((v.u >> 16) & 1u)) >> 16);
}
static __device__ __forceinline__ unsigned short f2bf_rh(float f) {
    union { float f; uint32_t u; } v; v.f = f;
    return (unsigned short)((v.u + 0x8000u) >> 16);
}

// ---------- wprep: coalesced LDS transpose, W -> WT f16 [320][256] ----------
__global__ __launch_bounds__(256) void wprep(
    const float* __restrict__ Wf, const float* __restrict__ Wg,
    const float* __restrict__ Wh, _Float16* __restrict__ WT)
{
    __shared__ float tile[64][33];
    const int t = blockIdx.x, kc = blockIdx.y, tid = threadIdx.x;
    const float* src; int stride;
    if (t == 0)      { src = Wf;                stride = 32;  }
    else if (t == 1) { src = Wg;                stride = 32;  }
    else             { src = Wh + (t - 2) * 32; stride = 256; }

    const int c = tid & 31, a = tid >> 5;
    #pragma unroll
    for (int p = 0; p < 8; p++) {
        int kk = p * 8 + a;
        tile[kk][c] = src[(size_t)(kc * 64 + kk) * stride + c];
    }
    __syncthreads();
    const int kk = tid & 63, aa = tid >> 6;
    #pragma unroll
    for (int p = 0; p < 8; p++) {
        int cc = p * 4 + aa;
        WT[(size_t)(t * 32 + cc) * 256 + kc * 64 + kk] = (_Float16)tile[kk][cc];
    }
}

// ---------- proj v7: 3 tiles/wave, x read 2x, batched reg-prefetch -----------
__global__ __launch_bounds__(256, 2) void proj_kernel(
    const float* __restrict__ x,
    const float* __restrict__ bfp, const float* __restrict__ bgp,
    const float* __restrict__ bhp,
    const _Float16* __restrict__ WT,
    _Float16* __restrict__ qf16, _Float16* __restrict__ kf16,
    unsigned short* __restrict__ v_frag)
{
    __shared__ __align__(16) _Float16 xs[64 * 256];            // 32 KB, swizzled
    __shared__ __align__(16) unsigned short tbuf[4][32 * 40];  // 10 KB

    const int tid  = threadIdx.x;
    const int lane = tid & 63;
    const int wave = tid >> 6;
    const int m_   = lane & 31;
    const int k8   = lane >> 5;
    const int row0 = blockIdx.x * 64;
    const int half = blockIdx.y;
    const int b    = row0 >> 12;
    const int n0   = row0 & 4095;
    const int kt   = n0 >> 6;

    #pragma unroll
    for (int i = 0; i < 8; i++) {
        int r  = 8 * i + (tid >> 5);
        int c5 = tid & 31;
        const f32x4* src = (const f32x4*)(x + (size_t)(row0 + r) * 256 + c5 * 8);
        f32x4 a = src[0], c4 = src[1];
        f16x8 h = { (_Float16)a.x, (_Float16)a.y, (_Float16)a.z, (_Float16)a.w,
                    (_Float16)c4.x, (_Float16)c4.y, (_Float16)c4.z, (_Float16)c4.w };
        int chunk = (((r >> 5) * 32 + c5)) * 32 + ((r & 31) ^ (c5 & 7));
        *(f16x8*)(xs + chunk * 8) = h;
    }
    __syncthreads();

    const int rowsub = wave & 1;
    const int tg     = wave >> 1;
    const int ntile  = (half == 0) ? 3 : 2;
    const int t_base = (half == 0) ? tg * 3 : 6 + tg * 2;
    const _Float16* wb[3];
    #pragma unroll
    for (int t = 0; t < 3; t++)
        wb[t] = WT + (size_t)((t_base + (t < ntile ? t : 0)) * 32 + m_) * 256 + k8 * 8;

    f32x16 acc[3];
    #pragma unroll
    for (int t = 0; t < 3; t++)
        #pragma unroll
        for (int i = 0; i < 16; i++) acc[t][i] = 0.f;

    f16x8 Bb[2][4][3];
    #pragma unroll
    for (int j = 0; j < 4; j++)
        #pragma unroll
        for (int t = 0; t < 3; t++) {
            if (t >= ntile) break;
            Bb[0][j][t] = *(const f16x8*)(wb[t] + j * 16);
        }
    #pragma unroll
    for (int g4 = 0; g4 < 4; g4++) {
        const int cur = g4 & 1, nxt = cur ^ 1;
        if (g4 < 3)
            #pragma unroll
            for (int j = 0; j < 4; j++)
                #pragma unroll
                for (int t = 0; t < 3; t++) {
                    if (t >= ntile) break;
                    Bb[nxt][j][t] = *(const f16x8*)(wb[t] + (g4 * 4 + 4 + j) * 16);
                }
        #pragma unroll
        for (int j = 0; j < 4; j++) {
            int ks = g4 * 4 + j;
            f16x8 A = *(const f16x8*)(xs + ((rowsub * 32 + ks * 2 + k8) * 32
                                            + (m_ ^ ((ks * 2 + k8) & 7))) * 8);
            #pragma unroll
            for (int t = 0; t < 3; t++) {
                if (t >= ntile) break;
                acc[t] = __builtin_amdgcn_mfma_f32_32x32x16_f16(A, Bb[cur][j][t],
                                                                acc[t], 0, 0, 0);
            }
        }
    }

    #pragma unroll
    for (int t = 0; t < 3; t++) {
        if (t >= ntile) break;
        const int tile = t_base + t;
        if (tile < 2) {            // f -> kf16, g -> qf16
            float bias = (tile == 0) ? bfp[m_] : bgp[m_];
            _Float16* dst = (tile == 0) ? kf16 : qf16;
            #pragma unroll
            for (int r = 0; r < 16; r++) {
                int m = (r & 3) + 8 * (r >> 2) + 4 * k8;
                int row = row0 + rowsub * 32 + m;
                dst[(size_t)row * 32 + m_] = (_Float16)(acc[t][r] + bias);
            }
        } else {                   // h -> v_frag[b][chg][kt][oct][chsl][ch32][key8]
            const int ht   = tile - 2;
            const int chgv = ht >> 2, chslv = ht & 3;
            float bias = bhp[ht * 32 + m_];
            unsigned short* buf = tbuf[wave];
            // per-wave buffer; DS ops from one wave execute in order -> no barrier
            #pragma unroll
            for (int u = 0; u < 8; u++) {
                int r = 2 * u;
                int m = (r & 3) + 8 * (r >> 2) + 4 * k8;
                uint32_t v = (uint32_t)f2bf(acc[t][r] + bias)
                           | ((uint32_t)f2bf(acc[t][r + 1] + bias) << 16);
                *(uint32_t*)(buf + m_ * 40 + m) = v;
            }
            #pragma unroll
            for (int u = 0; u < 2; u++) {
                int idx2 = u * 64 + lane;
                int chr = idx2 >> 2, q8 = idx2 & 3;
                s16x8 vv = *(const s16x8*)(buf + chr * 40 + q8 * 8);
                int oct = rowsub * 4 + q8;
                size_t e = (((((size_t)(b * 2 + chgv) * 64 + kt) * 8 + oct) * 4
                              + chslv) * 32 + chr) * 8;
                *(s16x8*)(v_frag + e) = vv;
            }
        }
    }
}

// ---------- flash attention v10: pipelined S -- S(it+1) overlaps PV(it) ------
// grid (64 qt, 4 b) = 256 blocks, 16 waves. Wave (qsub=w&1, j=w>>1):
// PV (all 16 waves, every iter): ch-slice j (32 ch) over the 128-key tile.
// S duty alternates by parity: wave computes S(t) for key-slice ksl=j&3 of its
// qsub when (t&1)==(j>>2). In iter it the duty half computes S(it+1) into
// P_s[(it+1)&1] while everyone runs PV(it) from P_s[it&1] -> the exp2 VALU
// chain and S-MFMAs overlap PV-MFMAs of sibling waves on the same SIMD; the
// single barrier per iter no longer serializes S before PV.
__global__ __launch_bounds__(1024, 4) void attn_kernel(
    const _Float16* __restrict__ qf16, const _Float16* __restrict__ kf16,
    const unsigned short* __restrict__ v_frag,
    const float* __restrict__ x, const float* __restrict__ gamma_p,
    float* __restrict__ out)
{
    __shared__ __align__(16) unsigned short P_s[2][2][4096]; // [par][qsub][16oct][32q][8]
    __shared__ __align__(16) float l_s[2][32][8];            // [qsub][q][wave j]

    const int tid  = threadIdx.x;
    const int lane = tid & 63;
    const int wave = tid >> 6;        // 0..15
    const int qsub = wave & 1;
    const int j    = wave >> 1;       // ch-slice 0..7
    const int ksl  = j & 3;           // S key-slice
    const int sgrp = j >> 2;          // S duty parity: computes S(t) iff (t&1)==sgrp
    const int m_   = lane & 31;
    const int k8   = lane >> 5;
    const int qt   = blockIdx.x;
    const int b    = blockIdx.y;
    const size_t bn = (size_t)b * N_;
    const int octw = ksl * 4 + (m_ >> 3);
    const int osw  = octw & 3;
    const int kofs = m_ & 7;

    // v_frag base for ch-slice j (chg = j>>2, chsl = j&3)
    const unsigned short* vb = v_frag + (size_t)(b * 2 + (j >> 2)) * 524288
                             + (j & 3) * 256 + m_ * 8;
    // frag(it, oct): vb + it*16384 + (oct>>3)*8192 + (oct&7)*1024, oct=0..15

    const int qrow = qt * 64 + qsub * 32 + m_;
    const f16x8 Aq0 = *(const f16x8*)(qf16 + (bn + qrow) * 32 + k8 * 8);
    const f16x8 Aq1 = *(const f16x8*)(qf16 + (bn + qrow) * 32 + 16 + k8 * 8);

    // first duty tile: group0 -> K(0), group1 -> K(1)
    const _Float16* kp0 = kf16 + (bn + sgrp * 128 + ksl * 32 + m_) * 32;
    f16x8 Kc0 = *(const f16x8*)(kp0 + k8 * 8);
    f16x8 Kc1 = *(const f16x8*)(kp0 + 16 + k8 * 8);

    f32x16 acc;
    float l_acc[16];
    #pragma unroll
    for (int i = 0; i < 16; i++) { acc[i] = 0.f; l_acc[i] = 0.f; }

    // prologue: duty group 0 computes S(0) -> P_s[0]
    if (sgrp == 0) {
        f32x16 s;
        #pragma unroll
        for (int i = 0; i < 16; i++) s[i] = 0.f;
        s = __builtin_amdgcn_mfma_f32_32x32x16_f16(Aq0, Kc0, s, 0, 0, 0);
        s = __builtin_amdgcn_mfma_f32_32x32x16_f16(Aq1, Kc1, s, 0, 0, 0);
        unsigned short* Pb = P_s[0][qsub];
        #pragma unroll
        for (int r = 0; r < 16; r++) {
            float p = __builtin_amdgcn_exp2f(fmaf(s[r], LOG2E, -SOFT_OFF));
            l_acc[r] += p;
            int q = (r & 3) + 8 * (r >> 2) + 4 * k8;
            Pb[(octw * 32 + (q ^ osw)) * 8 + kofs] = f2bf_rh(p);
        }
        const _Float16* kp = kf16 + (bn + 2 * 128 + ksl * 32 + m_) * 32;
        Kc0 = *(const f16x8*)(kp + k8 * 8);
        Kc1 = *(const f16x8*)(kp + 16 + k8 * 8);
    }
    // Bv batch0 prefetch for iter 0
    bf16x8 Bv0[4], Bv1[4];
    #pragma unroll
    for (int ks = 0; ks < 4; ks++)
        Bv0[ks] = *(const bf16x8*)(vb + (ks * 2 + k8) * 1024);
    __syncthreads();

    for (int it = 0; it < 32; it++) {
        const int par = it & 1;
        const int itn = (it < 31) ? it + 1 : 31;
        const bool duty = (((it + 1) & 1) == sgrp) && (it < 31);

        // Bv batch1 for current iter; latency covered by PV batch0
        #pragma unroll
        for (int ks = 0; ks < 4; ks++)
            Bv1[ks] = *(const bf16x8*)(vb + (size_t)it * 16384 + 8192
                                       + (ks * 2 + k8) * 1024);

        // S(it+1): issue QK^T MFMAs early; exp consumes after PV batch0
        f32x16 s;
        if (duty) {
            #pragma unroll
            for (int i = 0; i < 16; i++) s[i] = 0.f;
            s = __builtin_amdgcn_mfma_f32_32x32x16_f16(Aq0, Kc0, s, 0, 0, 0);
            s = __builtin_amdgcn_mfma_f32_32x32x16_f16(Aq1, Kc1, s, 0, 0, 0);
        }

        const unsigned short* Pr = P_s[par][qsub];
        #pragma unroll
        for (int ks = 0; ks < 4; ks++) {
            int oct = ks * 2 + k8;
            bf16x8 Ap = *(const bf16x8*)(Pr + (oct * 32 + (m_ ^ (oct & 3))) * 8);
            acc = __builtin_amdgcn_mfma_f32_32x32x16_bf16(Ap, Bv0[ks], acc, 0, 0, 0);
        }

        if (duty) {
            unsigned short* Pb = P_s[par ^ 1][qsub];
            #pragma unroll
            for (int r = 0; r < 16; r++) {
                float p = __builtin_amdgcn_exp2f(fmaf(s[r], LOG2E, -SOFT_OFF));
                l_acc[r] += p;
                int q = (r & 3) + 8 * (r >> 2) + 4 * k8;
                Pb[(octw * 32 + (q ^ osw)) * 8 + kofs] = f2bf_rh(p);
            }
            // K for this wave's next duty (2 iters ahead)
            int kt3 = (it + 3 < 32) ? (it + 3) : 31;
            const _Float16* kp = kf16 + (bn + (size_t)kt3 * 128 + ksl * 32 + m_) * 32;
            Kc0 = *(const f16x8*)(kp + k8 * 8);
            Kc1 = *(const f16x8*)(kp + 16 + k8 * 8);
        }

        #pragma unroll
        for (int ks = 0; ks < 4; ks++) {
            int oct = 8 + ks * 2 + k8;
            bf16x8 Ap = *(const bf16x8*)(Pr + (oct * 32 + (m_ ^ (oct & 3))) * 8);
            acc = __builtin_amdgcn_mfma_f32_32x32x16_bf16(Ap, Bv1[ks], acc, 0, 0, 0);
        }
        // Bv batch0 prefetch for next iter (stays in flight across the barrier)
        #pragma unroll
        for (int ks = 0; ks < 4; ks++)
            Bv0[ks] = *(const bf16x8*)(vb + (size_t)itn * 16384
                                       + (ks * 2 + k8) * 1024);
        __syncthreads();
    }

    // l: each wave reduces its duty tiles over 32 key-cols, publishes to l_s;
    // final l[q] = sum of 8 contributions (4 ksl x 2 parity groups)
    #pragma unroll
    for (int off = 1; off < 32; off <<= 1)
        #pragma unroll
        for (int r = 0; r < 16; r++)
            l_acc[r] += __shfl_xor(l_acc[r], off, 64);
    if (m_ == 0) {
        #pragma unroll
        for (int r = 0; r < 16; r++) {
            int q = (r & 3) + 8 * (r >> 2) + 4 * k8;
            l_s[qsub][q][j] = l_acc[r];
        }
    }
    __syncthreads();

    const float gamma = *gamma_p;
    #pragma unroll
    for (int r = 0; r < 16; r++) {
        int q = (r & 3) + 8 * (r >> 2) + 4 * k8;
        f32x4 la = *(const f32x4*)(&l_s[qsub][q][0]);
        f32x4 lb = *(const f32x4*)(&l_s[qsub][q][4]);
        float l = ((la.x + la.y) + (la.z + la.w))
                + ((lb.x + lb.y) + (lb.z + lb.w));
        size_t idx = (bn + qt * 64 + qsub * 32 + q) * 256 + j * 32 + m_;
        out[idx] = gamma * (acc[r] / l) + x[idx];
    }
}

extern "C" void kernel_launch(void* const* d_in, const int* in_sizes, int n_in,
                              void* d_out, int out_size, void* d_ws, size_t ws_size,
                              hipStream_t stream) {
    const float* x   = (const float*)d_in[0];
    const float* Wf  = (const float*)d_in[1];
    const float* bfp = (const float*)d_in[2];
    const float* Wg  = (const float*)d_in[3];
    const float* bgp = (const float*)d_in[4];
    const float* Wh  = (const float*)d_in[5];
    const float* bhp = (const float*)d_in[6];
    const float* gam = (const float*)d_in[7];
    float* out = (float*)d_out;

    unsigned char* ws = (unsigned char*)d_ws;
    const size_t MB = 1 << 20;
    _Float16* WT    = (_Float16*)(ws);              // [320][256] f16, 160 KB
    _Float16* qf16  = (_Float16*)(ws + 1 * MB);     // [B*N][32] f16 (queries g)
    _Float16* kf16  = (_Float16*)(ws + 2 * MB);     // [B*N][32] f16 (keys f)
    unsigned short* v_frag = (unsigned short*)(ws + 3 * MB);  // 8.4 MB B-frag layout

    wprep<<<dim3(10, 4), dim3(256), 0, stream>>>(Wf, Wg, Wh, WT);
    proj_kernel<<<dim3(256, 2), dim3(256), 0, stream>>>(
        x, bfp, bgp, bhp, WT, qf16, kf16, v_frag);
    attn_kernel<<<dim3(64, 4), dim3(1024), 0, stream>>>(
        qf16, kf16, v_frag, x, gam, out);
}

// Round 2
// 151.333 us; speedup vs baseline: 1.1649x; 1.1649x over previous
//
#include <hip/hip_runtime.h>
#include <stdint.h>

#define B_ 4
#define N_ 4096
#define C_ 256
#define LOG2E 1.44269504088896340736f
#define SOFT_OFF 88.0f

typedef float f32x4 __attribute__((ext_vector_type(4)));
typedef float f32x16 __attribute__((ext_vector_type(16)));
typedef short s16x8 __attribute__((ext_vector_type(8)));
typedef __bf16 bf16x8 __attribute__((ext_vector_type(8)));
typedef _Float16 f16x8 __attribute__((ext_vector_type(8)));

static __device__ __forceinline__ unsigned short f2bf(float f) {
    union { float f; uint32_t u; } v; v.f = f;
    return (unsigned short)((v.u + 0x7FFFu + ((v.u >> 16) & 1u)) >> 16);
}
static __device__ __forceinline__ unsigned short f2bf_rh(float f) {
    union { float f; uint32_t u; } v; v.f = f;
    return (unsigned short)((v.u + 0x8000u) >> 16);
}

// ---------- wprep: coalesced LDS transpose, W -> WT f16 [320][256] ----------
__global__ __launch_bounds__(256) void wprep(
    const float* __restrict__ Wf, const float* __restrict__ Wg,
    const float* __restrict__ Wh, _Float16* __restrict__ WT)
{
    __shared__ float tile[64][33];
    const int t = blockIdx.x, kc = blockIdx.y, tid = threadIdx.x;
    const float* src; int stride;
    if (t == 0)      { src = Wf;                stride = 32;  }
    else if (t == 1) { src = Wg;                stride = 32;  }
    else             { src = Wh + (t - 2) * 32; stride = 256; }

    const int c = tid & 31, a = tid >> 5;
    #pragma unroll
    for (int p = 0; p < 8; p++) {
        int kk = p * 8 + a;
        tile[kk][c] = src[(size_t)(kc * 64 + kk) * stride + c];
    }
    __syncthreads();
    const int kk = tid & 63, aa = tid >> 6;
    #pragma unroll
    for (int p = 0; p < 8; p++) {
        int cc = p * 4 + aa;
        WT[(size_t)(t * 32 + cc) * 256 + kc * 64 + kk] = (_Float16)tile[kk][cc];
    }
}

// ---------- proj v7: 3 tiles/wave, x read 2x, batched reg-prefetch -----------
__global__ __launch_bounds__(256, 2) void proj_kernel(
    const float* __restrict__ x,
    const float* __restrict__ bfp, const float* __restrict__ bgp,
    const float* __restrict__ bhp,
    const _Float16* __restrict__ WT,
    _Float16* __restrict__ qf16, _Float16* __restrict__ kf16,
    unsigned short* __restrict__ v_frag)
{
    __shared__ __align__(16) _Float16 xs[64 * 256];            // 32 KB, swizzled
    __shared__ __align__(16) unsigned short tbuf[4][32 * 40];  // 10 KB

    const int tid  = threadIdx.x;
    const int lane = tid & 63;
    const int wave = tid >> 6;
    const int m_   = lane & 31;
    const int k8   = lane >> 5;
    const int row0 = blockIdx.x * 64;
    const int half = blockIdx.y;
    const int b    = row0 >> 12;
    const int n0   = row0 & 4095;
    const int kt   = n0 >> 6;

    #pragma unroll
    for (int i = 0; i < 8; i++) {
        int r  = 8 * i + (tid >> 5);
        int c5 = tid & 31;
        const f32x4* src = (const f32x4*)(x + (size_t)(row0 + r) * 256 + c5 * 8);
        f32x4 a = src[0], c4 = src[1];
        f16x8 h = { (_Float16)a.x, (_Float16)a.y, (_Float16)a.z, (_Float16)a.w,
                    (_Float16)c4.x, (_Float16)c4.y, (_Float16)c4.z, (_Float16)c4.w };
        int chunk = (((r >> 5) * 32 + c5)) * 32 + ((r & 31) ^ (c5 & 7));
        *(f16x8*)(xs + chunk * 8) = h;
    }
    __syncthreads();

    const int rowsub = wave & 1;
    const int tg     = wave >> 1;
    const int ntile  = (half == 0) ? 3 : 2;
    const int t_base = (half == 0) ? tg * 3 : 6 + tg * 2;
    const _Float16* wb[3];
    #pragma unroll
    for (int t = 0; t < 3; t++)
        wb[t] = WT + (size_t)((t_base + (t < ntile ? t : 0)) * 32 + m_) * 256 + k8 * 8;

    f32x16 acc[3];
    #pragma unroll
    for (int t = 0; t < 3; t++)
        #pragma unroll
        for (int i = 0; i < 16; i++) acc[t][i] = 0.f;

    f16x8 Bb[2][4][3];
    #pragma unroll
    for (int j = 0; j < 4; j++)
        #pragma unroll
        for (int t = 0; t < 3; t++) {
            if (t >= ntile) break;
            Bb[0][j][t] = *(const f16x8*)(wb[t] + j * 16);
        }
    #pragma unroll
    for (int g4 = 0; g4 < 4; g4++) {
        const int cur = g4 & 1, nxt = cur ^ 1;
        if (g4 < 3)
            #pragma unroll
            for (int j = 0; j < 4; j++)
                #pragma unroll
                for (int t = 0; t < 3; t++) {
                    if (t >= ntile) break;
                    Bb[nxt][j][t] = *(const f16x8*)(wb[t] + (g4 * 4 + 4 + j) * 16);
                }
        #pragma unroll
        for (int j = 0; j < 4; j++) {
            int ks = g4 * 4 + j;
            f16x8 A = *(const f16x8*)(xs + ((rowsub * 32 + ks * 2 + k8) * 32
                                            + (m_ ^ ((ks * 2 + k8) & 7))) * 8);
            #pragma unroll
            for (int t = 0; t < 3; t++) {
                if (t >= ntile) break;
                acc[t] = __builtin_amdgcn_mfma_f32_32x32x16_f16(A, Bb[cur][j][t],
                                                                acc[t], 0, 0, 0);
            }
        }
    }

    #pragma unroll
    for (int t = 0; t < 3; t++) {
        if (t >= ntile) break;
        const int tile = t_base + t;
        if (tile < 2) {            // f -> kf16, g -> qf16
            float bias = (tile == 0) ? bfp[m_] : bgp[m_];
            _Float16* dst = (tile == 0) ? kf16 : qf16;
            #pragma unroll
            for (int r = 0; r < 16; r++) {
                int m = (r & 3) + 8 * (r >> 2) + 4 * k8;
                int row = row0 + rowsub * 32 + m;
                dst[(size_t)row * 32 + m_] = (_Float16)(acc[t][r] + bias);
            }
        } else {                   // h -> v_frag[b][chg][kt][oct][chsl][ch32][key8]
            const int ht   = tile - 2;
            const int chgv = ht >> 2, chslv = ht & 3;
            float bias = bhp[ht * 32 + m_];
            unsigned short* buf = tbuf[wave];
            // per-wave buffer; DS ops from one wave execute in order -> no barrier
            #pragma unroll
            for (int u = 0; u < 8; u++) {
                int r = 2 * u;
                int m = (r & 3) + 8 * (r >> 2) + 4 * k8;
                uint32_t v = (uint32_t)f2bf(acc[t][r] + bias)
                           | ((uint32_t)f2bf(acc[t][r + 1] + bias) << 16);
                *(uint32_t*)(buf + m_ * 40 + m) = v;
            }
            #pragma unroll
            for (int u = 0; u < 2; u++) {
                int idx2 = u * 64 + lane;
                int chr = idx2 >> 2, q8 = idx2 & 3;
                s16x8 vv = *(const s16x8*)(buf + chr * 40 + q8 * 8);
                int oct = rowsub * 4 + q8;
                size_t e = (((((size_t)(b * 2 + chgv) * 64 + kt) * 8 + oct) * 4
                              + chslv) * 32 + chr) * 8;
                *(s16x8*)(v_frag + e) = vv;
            }
        }
    }
}

// ---------- flash attention v11: pipelined S, contiguous duty block ----------
// grid (64 qt, 4 b) = 256 blocks, 16 waves. Wave (qsub=w&1, j=w>>1):
// PV (all 16 waves, every iter): ch-slice j (32 ch) over the 128-key tile.
// S duty alternates by parity: wave computes S(t) for key-slice ksl=j&3 of its
// qsub when (t&1)==(j>>2). The whole duty block (QK^T MFMA + exp2 + P write +
// K prefetch) sits BETWEEN PV batch0 and PV batch1 as one contiguous unit so
// the s[16] live range stays short (v10 stretched it across PV batch0 ->
// scratch spills, +37 MB HBM traffic, 62.8 -> 92.8 us regression).
// Overlap is wave-level: per SIMD, 2 duty waves (VALU/trans/DS) co-issue with
// 2 non-duty waves (pure MFMA). One barrier per iter (parity dbuf on P_s).
__global__ __launch_bounds__(1024, 4) void attn_kernel(
    const _Float16* __restrict__ qf16, const _Float16* __restrict__ kf16,
    const unsigned short* __restrict__ v_frag,
    const float* __restrict__ x, const float* __restrict__ gamma_p,
    float* __restrict__ out)
{
    __shared__ __align__(16) unsigned short P_s[2][2][4096]; // [par][qsub][16oct][32q][8]
    __shared__ __align__(16) float l_s[2][32][8];            // [qsub][q][wave j]

    const int tid  = threadIdx.x;
    const int lane = tid & 63;
    const int wave = tid >> 6;        // 0..15
    const int qsub = wave & 1;
    const int j    = wave >> 1;       // ch-slice 0..7
    const int ksl  = j & 3;           // S key-slice
    const int sgrp = j >> 2;          // S duty parity: computes S(t) iff (t&1)==sgrp
    const int m_   = lane & 31;
    const int k8   = lane >> 5;
    const int qt   = blockIdx.x;
    const int b    = blockIdx.y;
    const size_t bn = (size_t)b * N_;
    const int octw = ksl * 4 + (m_ >> 3);
    const int osw  = octw & 3;
    const int kofs = m_ & 7;

    // v_frag base for ch-slice j (chg = j>>2, chsl = j&3)
    const unsigned short* vb = v_frag + (size_t)(b * 2 + (j >> 2)) * 524288
                             + (j & 3) * 256 + m_ * 8;
    // frag(it, oct): vb + it*16384 + (oct>>3)*8192 + (oct&7)*1024, oct=0..15

    const int qrow = qt * 64 + qsub * 32 + m_;
    const f16x8 Aq0 = *(const f16x8*)(qf16 + (bn + qrow) * 32 + k8 * 8);
    const f16x8 Aq1 = *(const f16x8*)(qf16 + (bn + qrow) * 32 + 16 + k8 * 8);

    // first duty tile: group0 -> K(0), group1 -> K(1)
    const _Float16* kp0 = kf16 + (bn + sgrp * 128 + ksl * 32 + m_) * 32;
    f16x8 Kc0 = *(const f16x8*)(kp0 + k8 * 8);
    f16x8 Kc1 = *(const f16x8*)(kp0 + 16 + k8 * 8);

    f32x16 acc;
    float l_acc[16];
    #pragma unroll
    for (int i = 0; i < 16; i++) { acc[i] = 0.f; l_acc[i] = 0.f; }

    // prologue: duty group 0 computes S(0) -> P_s[0]
    if (sgrp == 0) {
        f32x16 s;
        #pragma unroll
        for (int i = 0; i < 16; i++) s[i] = 0.f;
        s = __builtin_amdgcn_mfma_f32_32x32x16_f16(Aq0, Kc0, s, 0, 0, 0);
        s = __builtin_amdgcn_mfma_f32_32x32x16_f16(Aq1, Kc1, s, 0, 0, 0);
        unsigned short* Pb = P_s[0][qsub];
        #pragma unroll
        for (int r = 0; r < 16; r++) {
            float p = __builtin_amdgcn_exp2f(fmaf(s[r], LOG2E, -SOFT_OFF));
            l_acc[r] += p;
            int q = (r & 3) + 8 * (r >> 2) + 4 * k8;
            Pb[(octw * 32 + (q ^ osw)) * 8 + kofs] = f2bf_rh(p);
        }
        const _Float16* kp = kf16 + (bn + 2 * 128 + ksl * 32 + m_) * 32;
        Kc0 = *(const f16x8*)(kp + k8 * 8);
        Kc1 = *(const f16x8*)(kp + 16 + k8 * 8);
    }
    // Bv batch0 prefetch for iter 0
    bf16x8 Bv0[4], Bv1[4];
    #pragma unroll
    for (int ks = 0; ks < 4; ks++)
        Bv0[ks] = *(const bf16x8*)(vb + (ks * 2 + k8) * 1024);
    __syncthreads();

    for (int it = 0; it < 32; it++) {
        const int par = it & 1;
        const int itn = (it < 31) ? it + 1 : 31;
        const bool duty = (((it + 1) & 1) == sgrp) && (it < 31);

        // Bv batch1 for current iter; latency covered by PV batch0
        #pragma unroll
        for (int ks = 0; ks < 4; ks++)
            Bv1[ks] = *(const bf16x8*)(vb + (size_t)it * 16384 + 8192
                                       + (ks * 2 + k8) * 1024);

        const unsigned short* Pr = P_s[par][qsub];
        #pragma unroll
        for (int ks = 0; ks < 4; ks++) {
            int oct = ks * 2 + k8;
            bf16x8 Ap = *(const bf16x8*)(Pr + (oct * 32 + (m_ ^ (oct & 3))) * 8);
            acc = __builtin_amdgcn_mfma_f32_32x32x16_bf16(Ap, Bv0[ks], acc, 0, 0, 0);
        }

        // S(it+1) as one contiguous block: MFMA -> exp2 -> P write -> K pf.
        // s[16] live range confined here (Bv0 regs are dead by now).
        if (duty) {
            f32x16 s;
            #pragma unroll
            for (int i = 0; i < 16; i++) s[i] = 0.f;
            s = __builtin_amdgcn_mfma_f32_32x32x16_f16(Aq0, Kc0, s, 0, 0, 0);
            s = __builtin_amdgcn_mfma_f32_32x32x16_f16(Aq1, Kc1, s, 0, 0, 0);
            unsigned short* Pb = P_s[par ^ 1][qsub];
            #pragma unroll
            for (int r = 0; r < 16; r++) {
                float p = __builtin_amdgcn_exp2f(fmaf(s[r], LOG2E, -SOFT_OFF));
                l_acc[r] += p;
                int q = (r & 3) + 8 * (r >> 2) + 4 * k8;
                Pb[(octw * 32 + (q ^ osw)) * 8 + kofs] = f2bf_rh(p);
            }
            // K for this wave's next duty (S(it+3), computed during it+2)
            int kt3 = (it + 3 < 32) ? (it + 3) : 31;
            const _Float16* kp = kf16 + (bn + (size_t)kt3 * 128 + ksl * 32 + m_) * 32;
            Kc0 = *(const f16x8*)(kp + k8 * 8);
            Kc1 = *(const f16x8*)(kp + 16 + k8 * 8);
        }

        #pragma unroll
        for (int ks = 0; ks < 4; ks++) {
            int oct = 8 + ks * 2 + k8;
            bf16x8 Ap = *(const bf16x8*)(Pr + (oct * 32 + (m_ ^ (oct & 3))) * 8);
            acc = __builtin_amdgcn_mfma_f32_32x32x16_bf16(Ap, Bv1[ks], acc, 0, 0, 0);
        }
        // Bv batch0 prefetch for next iter (stays in flight across the barrier)
        #pragma unroll
        for (int ks = 0; ks < 4; ks++)
            Bv0[ks] = *(const bf16x8*)(vb + (size_t)itn * 16384
                                       + (ks * 2 + k8) * 1024);
        __syncthreads();
    }

    // l: each wave reduces its duty tiles over 32 key-cols, publishes to l_s;
    // final l[q] = sum of 8 contributions (4 ksl x 2 parity groups)
    #pragma unroll
    for (int off = 1; off < 32; off <<= 1)
        #pragma unroll
        for (int r = 0; r < 16; r++)
            l_acc[r] += __shfl_xor(l_acc[r], off, 64);
    if (m_ == 0) {
        #pragma unroll
        for (int r = 0; r < 16; r++) {
            int q = (r & 3) + 8 * (r >> 2) + 4 * k8;
            l_s[qsub][q][j] = l_acc[r];
        }
    }
    __syncthreads();

    const float gamma = *gamma_p;
    #pragma unroll
    for (int r = 0; r < 16; r++) {
        int q = (r & 3) + 8 * (r >> 2) + 4 * k8;
        f32x4 la = *(const f32x4*)(&l_s[qsub][q][0]);
        f32x4 lb = *(const f32x4*)(&l_s[qsub][q][4]);
        float l = ((la.x + la.y) + (la.z + la.w))
                + ((lb.x + lb.y) + (lb.z + lb.w));
        size_t idx = (bn + qt * 64 + qsub * 32 + q) * 256 + j * 32 + m_;
        out[idx] = gamma * (acc[r] / l) + x[idx];
    }
}

extern "C" void kernel_launch(void* const* d_in, const int* in_sizes, int n_in,
                              void* d_out, int out_size, void* d_ws, size_t ws_size,
                              hipStream_t stream) {
    const float* x   = (const float*)d_in[0];
    const float* Wf  = (const float*)d_in[1];
    const float* bfp = (const float*)d_in[2];
    const float* Wg  = (const float*)d_in[3];
    const float* bgp = (const float*)d_in[4];
    const float* Wh  = (const float*)d_in[5];
    const float* bhp = (const float*)d_in[6];
    const float* gam = (const float*)d_in[7];
    float* out = (float*)d_out;

    unsigned char* ws = (unsigned char*)d_ws;
    const size_t MB = 1 << 20;
    _Float16* WT    = (_Float16*)(ws);              // [320][256] f16, 160 KB
    _Float16* qf16  = (_Float16*)(ws + 1 * MB);     // [B*N][32] f16 (queries g)
    _Float16* kf16  = (_Float16*)(ws + 2 * MB);     // [B*N][32] f16 (keys f)
    unsigned short* v_frag = (unsigned short*)(ws + 3 * MB);  // 8.4 MB B-frag layout

    wprep<<<dim3(10, 4), dim3(256), 0, stream>>>(Wf, Wg, Wh, WT);
    proj_kernel<<<dim3(256, 2), dim3(256), 0, stream>>>(
        x, bfp, bgp, bhp, WT, qf16, kf16, v_frag);
    attn_kernel<<<dim3(64, 4), dim3(1024), 0, stream>>>(
        qf16, kf16, v_frag, x, gam, out);
}